// Round 1
// baseline (1741.733 us; speedup 1.0000x reference)
//
#include <hip/hip_runtime.h>

#define N_NODES 50000
#define N_EDGES 800000
#define F_IN    512
#define HID     128
#define OUT_F   20

// ---------------- degree / norm ----------------

__global__ void k_deg_init(float* __restrict__ deg) {
    int i = blockIdx.x * blockDim.x + threadIdx.x;
    if (i < N_NODES) deg[i] = 1.0f;   // self-loop weight 1
}

__global__ void k_deg_acc(const int* __restrict__ col, const float* __restrict__ w,
                          float* __restrict__ deg) {
    int e = blockIdx.x * blockDim.x + threadIdx.x;
    if (e < N_EDGES) atomicAdd(&deg[col[e]], w[e]);
}

__global__ void k_dinv(float* __restrict__ deg) {  // in place deg -> rsqrt(deg)
    int i = blockIdx.x * blockDim.x + threadIdx.x;
    if (i < N_NODES) {
        float d = deg[i];
        deg[i] = d > 0.f ? rsqrtf(d) : 0.f;
    }
}

__global__ void k_norm(const int* __restrict__ row, const int* __restrict__ col,
                       const float* __restrict__ w, const float* __restrict__ dinv,
                       float* __restrict__ norm) {
    int e = blockIdx.x * blockDim.x + threadIdx.x;
    if (e < N_EDGES) norm[e] = dinv[row[e]] * w[e] * dinv[col[e]];
}

// ---------------- layer 1 GEMM: h = x @ W1  (50000x512 @ 512x128) ----------------
// 128 threads = one col each; 16 rows per block staged in LDS; W element reused 16x.

#define RPB 16

__global__ __launch_bounds__(128) void k_gemm1(const float* __restrict__ x,
                                               const float* __restrict__ W1,
                                               float* __restrict__ h) {
    __shared__ float xs[RPB][F_IN];
    const int r0 = blockIdx.x * RPB;
    const int n  = threadIdx.x;  // output col 0..127

    // cooperative float4 load of 16 rows of x (32 KB)
    const float4* xv = (const float4*)(x + (size_t)r0 * F_IN);
    float4* sv = (float4*)(&xs[0][0]);
    const int nv = RPB * F_IN / 4;  // 2048
    for (int t = threadIdx.x; t < nv; t += 128) sv[t] = xv[t];
    __syncthreads();

    float acc[RPB];
#pragma unroll
    for (int r = 0; r < RPB; ++r) acc[r] = 0.f;

    for (int k = 0; k < F_IN; k += 4) {
        float w0 = W1[(k + 0) * HID + n];
        float w1 = W1[(k + 1) * HID + n];
        float w2 = W1[(k + 2) * HID + n];
        float w3 = W1[(k + 3) * HID + n];
#pragma unroll
        for (int r = 0; r < RPB; ++r) {
            float4 x4 = *(const float4*)(&xs[r][k]);
            acc[r] = fmaf(x4.x, w0, acc[r]);
            acc[r] = fmaf(x4.y, w1, acc[r]);
            acc[r] = fmaf(x4.z, w2, acc[r]);
            acc[r] = fmaf(x4.w, w3, acc[r]);
        }
    }
#pragma unroll
    for (int r = 0; r < RPB; ++r) h[(size_t)(r0 + r) * HID + n] = acc[r];
}

// ---------------- aggregation layer 1 ----------------

__global__ void k_selfinit1(const float* __restrict__ h, const float* __restrict__ dinv,
                            float* __restrict__ agg) {
    size_t g = (size_t)blockIdx.x * blockDim.x + threadIdx.x;
    if (g < (size_t)N_NODES * HID) {
        int i = (int)(g >> 7);  // /HID
        float di = dinv[i];
        agg[g] = di * di * h[g];
    }
}

// 32 lanes per edge, float4 per lane
__global__ void k_scatter1(const int* __restrict__ row, const int* __restrict__ col,
                           const float* __restrict__ norm, const float* __restrict__ h,
                           float* __restrict__ agg) {
    size_t g = (size_t)blockIdx.x * blockDim.x + threadIdx.x;
    size_t e = g >> 5;
    if (e >= N_EDGES) return;
    int lane = (int)(g & 31);
    int r = row[e], c = col[e];
    float nm = norm[e];
    float4 hv = *(const float4*)(h + (size_t)r * HID + lane * 4);
    float* dst = agg + (size_t)c * HID + lane * 4;
    atomicAdd(dst + 0, hv.x * nm);
    atomicAdd(dst + 1, hv.y * nm);
    atomicAdd(dst + 2, hv.z * nm);
    atomicAdd(dst + 3, hv.w * nm);
}

__global__ void k_bias_relu(float* __restrict__ agg, const float* __restrict__ b1) {
    size_t g = (size_t)blockIdx.x * blockDim.x + threadIdx.x;
    if (g < (size_t)N_NODES * HID) {
        int j = (int)(g & (HID - 1));
        float v = agg[g] + b1[j];
        agg[g] = v > 0.f ? v : 0.f;
    }
}

// ---------------- layer 2 GEMM: h2 = h1 @ W2  (50000x128 @ 128x20) ----------------
// 32 lanes per row, lanes 0..19 active.

__global__ __launch_bounds__(256) void k_gemm2(const float* __restrict__ h1,
                                               const float* __restrict__ W2,
                                               float* __restrict__ h2) {
    int g = blockIdx.x * blockDim.x + threadIdx.x;
    int i = g >> 5;
    int j = g & 31;
    if (i >= N_NODES || j >= OUT_F) return;
    float acc = 0.f;
    const float* hr = h1 + (size_t)i * HID;
    for (int k = 0; k < HID; ++k) acc = fmaf(hr[k], W2[k * OUT_F + j], acc);
    h2[(size_t)i * OUT_F + j] = acc;
}

// ---------------- aggregation layer 2 (into d_out) ----------------

__global__ void k_outinit(const float* __restrict__ h2, const float* __restrict__ dinv,
                          const float* __restrict__ b2, float* __restrict__ out) {
    int g = blockIdx.x * blockDim.x + threadIdx.x;
    if (g < N_NODES * OUT_F) {
        int i = g / OUT_F;
        int j = g - i * OUT_F;
        float di = dinv[i];
        out[g] = di * di * h2[g] + b2[j];
    }
}

__global__ void k_scatter2(const int* __restrict__ row, const int* __restrict__ col,
                           const float* __restrict__ norm, const float* __restrict__ h2,
                           float* __restrict__ out) {
    size_t g = (size_t)blockIdx.x * blockDim.x + threadIdx.x;
    size_t e = g >> 5;
    if (e >= N_EDGES) return;
    int j = (int)(g & 31);
    if (j >= OUT_F) return;
    int r = row[e], c = col[e];
    float nm = norm[e];
    atomicAdd(&out[(size_t)c * OUT_F + j], h2[(size_t)r * OUT_F + j] * nm);
}

// ---------------- launch ----------------

extern "C" void kernel_launch(void* const* d_in, const int* in_sizes, int n_in,
                              void* d_out, int out_size, void* d_ws, size_t ws_size,
                              hipStream_t stream) {
    const float* x    = (const float*)d_in[0];
    const int*   ei   = (const int*)d_in[1];       // [2][E]
    const float* ew   = (const float*)d_in[2];
    const float* W1   = (const float*)d_in[3];
    const float* b1   = (const float*)d_in[4];
    const float* W2   = (const float*)d_in[5];
    const float* b2   = (const float*)d_in[6];
    float* out = (float*)d_out;

    const int* row = ei;
    const int* col = ei + N_EDGES;

    float* ws   = (float*)d_ws;
    float* dinv = ws;                          // 50000
    float* norm = dinv + N_NODES;              // 800000
    float* h    = norm + N_EDGES;              // 6.4M
    float* agg1 = h + (size_t)N_NODES * HID;   // 6.4M (becomes h1 in place)
    float* h2   = agg1 + (size_t)N_NODES * HID;// 1M

    // norm precompute
    k_deg_init<<<(N_NODES + 255) / 256, 256, 0, stream>>>(dinv);
    k_deg_acc<<<(N_EDGES + 255) / 256, 256, 0, stream>>>(col, ew, dinv);
    k_dinv<<<(N_NODES + 255) / 256, 256, 0, stream>>>(dinv);
    k_norm<<<(N_EDGES + 255) / 256, 256, 0, stream>>>(row, col, ew, dinv, norm);

    // layer 1
    k_gemm1<<<N_NODES / RPB, 128, 0, stream>>>(x, W1, h);
    k_selfinit1<<<(int)(((size_t)N_NODES * HID + 255) / 256), 256, 0, stream>>>(h, dinv, agg1);
    k_scatter1<<<(int)(((size_t)N_EDGES * 32 + 255) / 256), 256, 0, stream>>>(row, col, norm, h, agg1);
    k_bias_relu<<<(int)(((size_t)N_NODES * HID + 255) / 256), 256, 0, stream>>>(agg1, b1);

    // layer 2
    k_gemm2<<<(N_NODES * 32 + 255) / 256, 256, 0, stream>>>(agg1, W2, h2);
    k_outinit<<<(N_NODES * OUT_F + 255) / 256, 256, 0, stream>>>(h2, dinv, b2, out);
    k_scatter2<<<(int)(((size_t)N_EDGES * 32 + 255) / 256), 256, 0, stream>>>(row, col, norm, h2, out);
}

// Round 2
// 611.154 us; speedup vs baseline: 2.8499x; 2.8499x over previous
//
#include <hip/hip_runtime.h>

#define N_NODES 50000
#define N_EDGES 800000
#define F_IN    512
#define HID     128
#define OUT_F   20
#define SCAN_B  256
#define N_BLK   ((N_NODES + SCAN_B - 1) / SCAN_B)   // 196

// ---------------- degree + edge-count histogram ----------------

__global__ void k_init(float* __restrict__ deg, int* __restrict__ count) {
    int i = blockIdx.x * blockDim.x + threadIdx.x;
    if (i < N_NODES) { deg[i] = 1.0f; count[i] = 0; }  // self-loop weight 1
}

__global__ void k_deg_count(const int* __restrict__ col, const float* __restrict__ w,
                            float* __restrict__ deg, int* __restrict__ count) {
    int e = blockIdx.x * blockDim.x + threadIdx.x;
    if (e < N_EDGES) {
        int c = col[e];
        atomicAdd(&deg[c], w[e]);
        atomicAdd(&count[c], 1);
    }
}

__global__ void k_dinv(float* __restrict__ deg) {  // in place deg -> rsqrt(deg)
    int i = blockIdx.x * blockDim.x + threadIdx.x;
    if (i < N_NODES) {
        float d = deg[i];
        deg[i] = d > 0.f ? rsqrtf(d) : 0.f;
    }
}

__global__ void k_norm(const int* __restrict__ row, const int* __restrict__ col,
                       const float* __restrict__ w, const float* __restrict__ dinv,
                       float* __restrict__ norm) {
    int e = blockIdx.x * blockDim.x + threadIdx.x;
    if (e < N_EDGES) norm[e] = dinv[row[e]] * w[e] * dinv[col[e]];
}

// ---------------- scan (counting-sort offsets) ----------------

__global__ __launch_bounds__(SCAN_B) void k_scan1(const int* __restrict__ count,
                                                  int* __restrict__ bsum) {
    __shared__ int s[SCAN_B];
    int i = blockIdx.x * SCAN_B + threadIdx.x;
    s[threadIdx.x] = (i < N_NODES) ? count[i] : 0;
    __syncthreads();
    for (int off = SCAN_B / 2; off > 0; off >>= 1) {
        if (threadIdx.x < off) s[threadIdx.x] += s[threadIdx.x + off];
        __syncthreads();
    }
    if (threadIdx.x == 0) bsum[blockIdx.x] = s[0];
}

__global__ __launch_bounds__(SCAN_B) void k_scan2(int* __restrict__ bsum,
                                                  int* __restrict__ start) {
    __shared__ int s[SCAN_B];
    int tid = threadIdx.x;
    int v = (tid < N_BLK) ? bsum[tid] : 0;
    s[tid] = v;
    __syncthreads();
    for (int off = 1; off < SCAN_B; off <<= 1) {
        int t = (tid >= off) ? s[tid - off] : 0;
        __syncthreads();
        s[tid] += t;
        __syncthreads();
    }
    if (tid < N_BLK) bsum[tid] = s[tid] - v;   // exclusive
    if (tid == 0) start[N_NODES] = N_EDGES;
}

__global__ __launch_bounds__(SCAN_B) void k_scan3(const int* __restrict__ count,
                                                  const int* __restrict__ bsum,
                                                  int* __restrict__ start,
                                                  int* __restrict__ cursor) {
    __shared__ int s[SCAN_B];
    int i = blockIdx.x * SCAN_B + threadIdx.x;
    int tid = threadIdx.x;
    int v = (i < N_NODES) ? count[i] : 0;
    s[tid] = v;
    __syncthreads();
    for (int off = 1; off < SCAN_B; off <<= 1) {
        int t = (tid >= off) ? s[tid - off] : 0;
        __syncthreads();
        s[tid] += t;
        __syncthreads();
    }
    if (i < N_NODES) {
        int st = bsum[blockIdx.x] + s[tid] - v;  // exclusive scan
        start[i] = st;
        cursor[i] = st;
    }
}

__global__ void k_fill(const int* __restrict__ col, int* __restrict__ cursor,
                       int* __restrict__ eids) {
    int e = blockIdx.x * blockDim.x + threadIdx.x;
    if (e < N_EDGES) {
        int pos = atomicAdd(&cursor[col[e]], 1);
        eids[pos] = e;
    }
}

// ---------------- layer 1 GEMM: h = x @ W1  (50000x512 @ 512x128) ----------------

#define RPB 16

__global__ __launch_bounds__(128) void k_gemm1(const float* __restrict__ x,
                                               const float* __restrict__ W1,
                                               float* __restrict__ h) {
    __shared__ float xs[RPB][F_IN];
    const int r0 = blockIdx.x * RPB;
    const int n  = threadIdx.x;  // output col 0..127

    const float4* xv = (const float4*)(x + (size_t)r0 * F_IN);
    float4* sv = (float4*)(&xs[0][0]);
    const int nv = RPB * F_IN / 4;  // 2048
    for (int t = threadIdx.x; t < nv; t += 128) sv[t] = xv[t];
    __syncthreads();

    float acc[RPB];
#pragma unroll
    for (int r = 0; r < RPB; ++r) acc[r] = 0.f;

    for (int k = 0; k < F_IN; k += 4) {
        float w0 = W1[(k + 0) * HID + n];
        float w1 = W1[(k + 1) * HID + n];
        float w2 = W1[(k + 2) * HID + n];
        float w3 = W1[(k + 3) * HID + n];
#pragma unroll
        for (int r = 0; r < RPB; ++r) {
            float4 x4 = *(const float4*)(&xs[r][k]);
            acc[r] = fmaf(x4.x, w0, acc[r]);
            acc[r] = fmaf(x4.y, w1, acc[r]);
            acc[r] = fmaf(x4.z, w2, acc[r]);
            acc[r] = fmaf(x4.w, w3, acc[r]);
        }
    }
#pragma unroll
    for (int r = 0; r < RPB; ++r) h[(size_t)(r0 + r) * HID + n] = acc[r];
}

// ---------------- layer 1 aggregation: gather (one block per node) ----------------

__global__ __launch_bounds__(128) void k_agg1(const int* __restrict__ row,
                                              const int* __restrict__ eids,
                                              const int* __restrict__ start,
                                              const float* __restrict__ norm,
                                              const float* __restrict__ h,
                                              const float* __restrict__ dinv,
                                              const float* __restrict__ b1,
                                              float* __restrict__ h1) {
    int c = blockIdx.x;
    int j = threadIdx.x;
    float di = dinv[c];
    float acc = di * di * h[(size_t)c * HID + j];   // self-loop
    int s0 = start[c], s1 = start[c + 1];
    for (int k = s0; k < s1; ++k) {
        int e = eids[k];
        float nm = norm[e];
        int r = row[e];
        acc = fmaf(nm, h[(size_t)r * HID + j], acc);
    }
    acc += b1[j];
    h1[(size_t)c * HID + j] = acc > 0.f ? acc : 0.f;  // relu
}

// ---------------- layer 2 GEMM: h2 = h1 @ W2  (50000x128 @ 128x20) ----------------

__global__ __launch_bounds__(256) void k_gemm2(const float* __restrict__ h1,
                                               const float* __restrict__ W2,
                                               float* __restrict__ h2) {
    int g = blockIdx.x * blockDim.x + threadIdx.x;
    int i = g >> 5;
    int j = g & 31;
    if (i >= N_NODES || j >= OUT_F) return;
    float acc = 0.f;
    const float* hr = h1 + (size_t)i * HID;
    for (int k = 0; k < HID; ++k) acc = fmaf(hr[k], W2[k * OUT_F + j], acc);
    h2[(size_t)i * OUT_F + j] = acc;
}

// ---------------- layer 2 aggregation: gather (32 lanes per node) ----------------

__global__ __launch_bounds__(256) void k_agg2(const int* __restrict__ row,
                                              const int* __restrict__ eids,
                                              const int* __restrict__ start,
                                              const float* __restrict__ norm,
                                              const float* __restrict__ h2,
                                              const float* __restrict__ dinv,
                                              const float* __restrict__ b2,
                                              float* __restrict__ out) {
    int g = blockIdx.x * blockDim.x + threadIdx.x;
    int c = g >> 5;
    int j = g & 31;
    if (c >= N_NODES || j >= OUT_F) return;
    float di = dinv[c];
    float acc = di * di * h2[(size_t)c * OUT_F + j] + b2[j];
    int s0 = start[c], s1 = start[c + 1];
    for (int k = s0; k < s1; ++k) {
        int e = eids[k];
        acc = fmaf(norm[e], h2[(size_t)row[e] * OUT_F + j], acc);
    }
    out[(size_t)c * OUT_F + j] = acc;
}

// ---------------- launch ----------------

extern "C" void kernel_launch(void* const* d_in, const int* in_sizes, int n_in,
                              void* d_out, int out_size, void* d_ws, size_t ws_size,
                              hipStream_t stream) {
    const float* x    = (const float*)d_in[0];
    const int*   ei   = (const int*)d_in[1];       // [2][E]
    const float* ew   = (const float*)d_in[2];
    const float* W1   = (const float*)d_in[3];
    const float* b1   = (const float*)d_in[4];
    const float* W2   = (const float*)d_in[5];
    const float* b2   = (const float*)d_in[6];
    float* out = (float*)d_out;

    const int* row = ei;
    const int* col = ei + N_EDGES;

    float* ws   = (float*)d_ws;
    float* dinv = ws;                               // N
    float* norm = dinv + N_NODES;                   // E
    float* h    = norm + N_EDGES;                   // N*HID
    float* h1   = h + (size_t)N_NODES * HID;        // N*HID
    float* h2   = h1 + (size_t)N_NODES * HID;       // N*OUT
    int* count  = (int*)(h2 + (size_t)N_NODES * OUT_F);  // N
    int* startp = count + N_NODES;                  // N+1
    int* cursor = startp + N_NODES + 1;             // N
    int* eids   = cursor + N_NODES;                 // E
    int* bsum   = eids + N_EDGES;                   // N_BLK

    // norm + CSR build
    k_init<<<N_BLK, 256, 0, stream>>>(dinv, count);
    k_deg_count<<<(N_EDGES + 255) / 256, 256, 0, stream>>>(col, ew, dinv, count);
    k_dinv<<<N_BLK, 256, 0, stream>>>(dinv);
    k_norm<<<(N_EDGES + 255) / 256, 256, 0, stream>>>(row, col, ew, dinv, norm);
    k_scan1<<<N_BLK, SCAN_B, 0, stream>>>(count, bsum);
    k_scan2<<<1, SCAN_B, 0, stream>>>(bsum, startp);
    k_scan3<<<N_BLK, SCAN_B, 0, stream>>>(count, bsum, startp, cursor);
    k_fill<<<(N_EDGES + 255) / 256, 256, 0, stream>>>(col, cursor, eids);

    // layer 1
    k_gemm1<<<N_NODES / RPB, 128, 0, stream>>>(x, W1, h);
    k_agg1<<<N_NODES, 128, 0, stream>>>(row, eids, startp, norm, h, dinv, b1, h1);

    // layer 2
    k_gemm2<<<(N_NODES * 32 + 255) / 256, 256, 0, stream>>>(h1, W2, h2);
    k_agg2<<<(N_NODES * 32 + 255) / 256, 256, 0, stream>>>(row, eids, startp, norm, h2, dinv, b2, out);
}

// Round 3
// 353.538 us; speedup vs baseline: 4.9266x; 1.7287x over previous
//
#include <hip/hip_runtime.h>

#define N_NODES 50000
#define N_EDGES 800000
#define F_IN    512
#define HID     128
#define OUT_F   20
#define SCAN_B  256
#define N_BLK   ((N_NODES + SCAN_B - 1) / SCAN_B)   // 196

typedef __bf16 bf16x8 __attribute__((ext_vector_type(8)));
typedef float  f32x4  __attribute__((ext_vector_type(4)));

// ---------------- degree + edge-count histogram ----------------

__global__ void k_init(float* __restrict__ deg, int* __restrict__ count) {
    int i = blockIdx.x * blockDim.x + threadIdx.x;
    if (i < N_NODES) { deg[i] = 1.0f; count[i] = 0; }  // self-loop weight 1
}

__global__ void k_deg_count(const int* __restrict__ col, const float* __restrict__ w,
                            float* __restrict__ deg, int* __restrict__ count) {
    int e = blockIdx.x * blockDim.x + threadIdx.x;
    if (e < N_EDGES) {
        int c = col[e];
        atomicAdd(&deg[c], w[e]);
        atomicAdd(&count[c], 1);
    }
}

__global__ void k_dinv(float* __restrict__ deg) {
    int i = blockIdx.x * blockDim.x + threadIdx.x;
    if (i < N_NODES) {
        float d = deg[i];
        deg[i] = d > 0.f ? rsqrtf(d) : 0.f;
    }
}

__global__ void k_norm(const int* __restrict__ row, const int* __restrict__ col,
                       const float* __restrict__ w, const float* __restrict__ dinv,
                       float* __restrict__ norm) {
    int e = blockIdx.x * blockDim.x + threadIdx.x;
    if (e < N_EDGES) norm[e] = dinv[row[e]] * w[e] * dinv[col[e]];
}

// ---------------- scan (counting-sort offsets) ----------------

__global__ __launch_bounds__(SCAN_B) void k_scan1(const int* __restrict__ count,
                                                  int* __restrict__ bsum) {
    __shared__ int s[SCAN_B];
    int i = blockIdx.x * SCAN_B + threadIdx.x;
    s[threadIdx.x] = (i < N_NODES) ? count[i] : 0;
    __syncthreads();
    for (int off = SCAN_B / 2; off > 0; off >>= 1) {
        if (threadIdx.x < off) s[threadIdx.x] += s[threadIdx.x + off];
        __syncthreads();
    }
    if (threadIdx.x == 0) bsum[blockIdx.x] = s[0];
}

__global__ __launch_bounds__(SCAN_B) void k_scan2(int* __restrict__ bsum,
                                                  int* __restrict__ start) {
    __shared__ int s[SCAN_B];
    int tid = threadIdx.x;
    int v = (tid < N_BLK) ? bsum[tid] : 0;
    s[tid] = v;
    __syncthreads();
    for (int off = 1; off < SCAN_B; off <<= 1) {
        int t = (tid >= off) ? s[tid - off] : 0;
        __syncthreads();
        s[tid] += t;
        __syncthreads();
    }
    if (tid < N_BLK) bsum[tid] = s[tid] - v;   // exclusive
    if (tid == 0) start[N_NODES] = N_EDGES;
}

__global__ __launch_bounds__(SCAN_B) void k_scan3(const int* __restrict__ count,
                                                  const int* __restrict__ bsum,
                                                  int* __restrict__ start,
                                                  int* __restrict__ cursor) {
    __shared__ int s[SCAN_B];
    int i = blockIdx.x * SCAN_B + threadIdx.x;
    int tid = threadIdx.x;
    int v = (i < N_NODES) ? count[i] : 0;
    s[tid] = v;
    __syncthreads();
    for (int off = 1; off < SCAN_B; off <<= 1) {
        int t = (tid >= off) ? s[tid - off] : 0;
        __syncthreads();
        s[tid] += t;
        __syncthreads();
    }
    if (i < N_NODES) {
        int st = bsum[blockIdx.x] + s[tid] - v;
        start[i] = st;
        cursor[i] = st;
    }
}

// fill: counting-sort edges by destination; store pre-gathered (row, norm)
__global__ void k_fill(const int* __restrict__ row, const int* __restrict__ col,
                       const float* __restrict__ norm, int* __restrict__ cursor,
                       int* __restrict__ rows_s, float* __restrict__ norms_s) {
    int e = blockIdx.x * blockDim.x + threadIdx.x;
    if (e < N_EDGES) {
        int pos = atomicAdd(&cursor[col[e]], 1);
        rows_s[pos] = row[e];
        norms_s[pos] = norm[e];
    }
}

// ---------------- W1 transpose + bf16 convert: w1t[n][k] = bf16(W1[k][n]) ----------------

__global__ void k_cvt_w1(const float* __restrict__ W1, __bf16* __restrict__ w1t) {
    int g = blockIdx.x * blockDim.x + threadIdx.x;   // g = k*HID + n
    if (g < F_IN * HID) {
        int k = g >> 7;
        int n = g & (HID - 1);
        w1t[(size_t)n * F_IN + k] = (__bf16)W1[g];
    }
}

// ---------------- layer 1 GEMM (MFMA bf16): hb = bf16(x @ W1) ----------------
// 128x128 block tile, 4 waves in 2x2, each wave 64x64 (4x4 frags of 16x16x32).
// A staged fp32->bf16 through XOR-swizzled, frag-permuted LDS; B read from w1t (L2).
// Frag k-layout (16x16x32): elem j -> k = (lane>>4)*4 + (j&3) + 16*(j>>2).

#define BKK 64

__global__ __launch_bounds__(256) void k_gemm1_mfma(const float* __restrict__ x,
                                                    const __bf16* __restrict__ w1t,
                                                    __bf16* __restrict__ hb) {
    __shared__ __bf16 As[128 * BKK];   // 16 KB, swizzled + k-permuted
    const int tid  = threadIdx.x;
    const int lane = tid & 63;
    const int wid  = tid >> 6;
    const int wm   = wid >> 1;         // row half
    const int wn   = wid & 1;          // col half
    const int r0   = blockIdx.x * 128;

    f32x4 acc[4][4] = {};              // [mi][ni]

    for (int k0 = 0; k0 < F_IN; k0 += BKK) {
        // ---- stage A: 128 rows x 64 k, fp32 -> bf16 ----
#pragma unroll
        for (int i = 0; i < 8; ++i) {
            int c   = tid + 256 * i;       // 16B-chunk id, 2048 total
            int r   = c >> 4;              // row 0..127
            int cin = c & 15;              // 4-float chunk in row (k = cin*4)
            int gr  = r0 + r;
            float4 v = make_float4(0.f, 0.f, 0.f, 0.f);
            if (gr < N_NODES)
                v = *(const float4*)(x + (size_t)gr * F_IN + k0 + cin * 4);
            union { __bf16 b[4]; uint2 u; } pk;
            pk.b[0] = (__bf16)v.x; pk.b[1] = (__bf16)v.y;
            pk.b[2] = (__bf16)v.z; pk.b[3] = (__bf16)v.w;
            // frag-permuted k order: within 32-k block b32, quad r4 -> slot (r4&3)*2+(r4>>2)
            int b32 = cin >> 3;
            int r4  = cin & 7;
            int slot = ((r4 & 3) << 1) | (r4 >> 2);
            int byte = r * (BKK * 2) + (((b32 << 6) + (slot << 3)) ^ ((r & 7) << 4));
            *(uint2*)((char*)As + byte) = pk.u;
        }
        __syncthreads();

        // ---- compute: 2 kk-steps of K=32 ----
#pragma unroll
        for (int kk = 0; kk < 2; ++kk) {
            bf16x8 a[4], b[4];
#pragma unroll
            for (int mi = 0; mi < 4; ++mi) {
                int r = wm * 64 + mi * 16 + (lane & 15);
                int byte = r * (BKK * 2) + (((kk << 6) + ((lane >> 4) << 4)) ^ ((r & 7) << 4));
                a[mi] = *(const bf16x8*)((char*)As + byte);
            }
#pragma unroll
            for (int ni = 0; ni < 4; ++ni) {
                int cc = wn * 64 + ni * 16 + (lane & 15);
                const __bf16* bp = w1t + (size_t)cc * F_IN + k0 + kk * 32 + ((lane >> 4) << 2);
                union { __bf16 h[8]; bf16x8 v; } bb;
                *(uint2*)(&bb.h[0]) = *(const uint2*)(bp);        // k quad
                *(uint2*)(&bb.h[4]) = *(const uint2*)(bp + 16);   // k+16 quad
                b[ni] = bb.v;
            }
#pragma unroll
            for (int mi = 0; mi < 4; ++mi)
#pragma unroll
                for (int ni = 0; ni < 4; ++ni)
                    acc[mi][ni] = __builtin_amdgcn_mfma_f32_16x16x32_bf16(
                        a[mi], b[ni], acc[mi][ni], 0, 0, 0);
        }
        __syncthreads();
    }

    // ---- epilogue: C/D layout col=lane&15, row=(lane>>4)*4+reg ----
#pragma unroll
    for (int mi = 0; mi < 4; ++mi) {
        int rb = r0 + wm * 64 + mi * 16 + ((lane >> 4) << 2);
#pragma unroll
        for (int r = 0; r < 4; ++r) {
            int gr = rb + r;
            if (gr < N_NODES) {
#pragma unroll
                for (int ni = 0; ni < 4; ++ni) {
                    int cc = wn * 64 + ni * 16 + (lane & 15);
                    hb[(size_t)gr * HID + cc] = (__bf16)acc[mi][ni][r];
                }
            }
        }
    }
}

// ---------------- layer 1 aggregation: gather, edge metadata staged in LDS ----------------

__global__ __launch_bounds__(128) void k_agg1(const int* __restrict__ rows_s,
                                              const float* __restrict__ norms_s,
                                              const int* __restrict__ start,
                                              const __bf16* __restrict__ hb,
                                              const float* __restrict__ dinv,
                                              const float* __restrict__ b1,
                                              float* __restrict__ h1) {
    __shared__ int   sr[128];
    __shared__ float sn[128];
    int c = blockIdx.x;
    int j = threadIdx.x;
    float di = dinv[c];
    float acc = di * di * (float)hb[(size_t)c * HID + j];   // self-loop
    int s0 = start[c], s1 = start[c + 1];
    for (int base = s0; base < s1; base += 128) {
        int m = s1 - base; if (m > 128) m = 128;
        __syncthreads();
        if (j < m) { sr[j] = rows_s[base + j]; sn[j] = norms_s[base + j]; }
        __syncthreads();
        for (int t = 0; t < m; ++t)
            acc = fmaf(sn[t], (float)hb[(size_t)sr[t] * HID + j], acc);
    }
    acc += b1[j];
    h1[(size_t)c * HID + j] = acc > 0.f ? acc : 0.f;        // relu
}

// ---------------- layer 2 GEMM: h2 = h1 @ W2  (50000x128 @ 128x20) ----------------

__global__ __launch_bounds__(256) void k_gemm2(const float* __restrict__ h1,
                                               const float* __restrict__ W2,
                                               float* __restrict__ h2) {
    int g = blockIdx.x * blockDim.x + threadIdx.x;
    int i = g >> 5;
    int j = g & 31;
    if (i >= N_NODES || j >= OUT_F) return;
    float acc = 0.f;
    const float* hr = h1 + (size_t)i * HID;
    for (int k = 0; k < HID; ++k) acc = fmaf(hr[k], W2[k * OUT_F + j], acc);
    h2[(size_t)i * OUT_F + j] = acc;
}

// ---------------- layer 2 aggregation ----------------

__global__ __launch_bounds__(256) void k_agg2(const int* __restrict__ rows_s,
                                              const float* __restrict__ norms_s,
                                              const int* __restrict__ start,
                                              const float* __restrict__ h2,
                                              const float* __restrict__ dinv,
                                              const float* __restrict__ b2,
                                              float* __restrict__ out) {
    int g = blockIdx.x * blockDim.x + threadIdx.x;
    int c = g >> 5;
    int j = g & 31;
    if (c >= N_NODES || j >= OUT_F) return;
    float di = dinv[c];
    float acc = di * di * h2[(size_t)c * OUT_F + j] + b2[j];
    int s0 = start[c], s1 = start[c + 1];
    for (int k = s0; k < s1; ++k)
        acc = fmaf(norms_s[k], h2[(size_t)rows_s[k] * OUT_F + j], acc);
    out[(size_t)c * OUT_F + j] = acc;
}

// ---------------- launch ----------------

extern "C" void kernel_launch(void* const* d_in, const int* in_sizes, int n_in,
                              void* d_out, int out_size, void* d_ws, size_t ws_size,
                              hipStream_t stream) {
    const float* x  = (const float*)d_in[0];
    const int*   ei = (const int*)d_in[1];       // [2][E] int32
    const float* ew = (const float*)d_in[2];
    const float* W1 = (const float*)d_in[3];
    const float* b1 = (const float*)d_in[4];
    const float* W2 = (const float*)d_in[5];
    const float* b2 = (const float*)d_in[6];
    float* out = (float*)d_out;

    const int* row = ei;
    const int* col = ei + N_EDGES;

    // workspace layout (all offsets 16B-aligned)
    char* p = (char*)d_ws;
    float* dinv    = (float*)p;  p += (size_t)N_NODES * 4;
    float* norm    = (float*)p;  p += (size_t)N_EDGES * 4;
    float* h1      = (float*)p;  p += (size_t)N_NODES * HID * 4;
    float* h2      = (float*)p;  p += (size_t)N_NODES * OUT_F * 4;
    float* norms_s = (float*)p;  p += (size_t)N_EDGES * 4;
    __bf16* hb     = (__bf16*)p; p += (size_t)N_NODES * HID * 2;
    __bf16* w1t    = (__bf16*)p; p += (size_t)F_IN * HID * 2;
    int* count     = (int*)p;    p += (size_t)N_NODES * 4;
    int* cursor    = (int*)p;    p += (size_t)N_NODES * 4;
    int* rows_s    = (int*)p;    p += (size_t)N_EDGES * 4;
    int* bsum      = (int*)p;    p += (size_t)N_BLK * 4;
    int* startp    = (int*)p;    p += (size_t)(N_NODES + 1) * 4;

    // norm + CSR build
    k_init<<<N_BLK, 256, 0, stream>>>(dinv, count);
    k_deg_count<<<(N_EDGES + 255) / 256, 256, 0, stream>>>(col, ew, dinv, count);
    k_dinv<<<N_BLK, 256, 0, stream>>>(dinv);
    k_norm<<<(N_EDGES + 255) / 256, 256, 0, stream>>>(row, col, ew, dinv, norm);
    k_scan1<<<N_BLK, SCAN_B, 0, stream>>>(count, bsum);
    k_scan2<<<1, SCAN_B, 0, stream>>>(bsum, startp);
    k_scan3<<<N_BLK, SCAN_B, 0, stream>>>(count, bsum, startp, cursor);
    k_fill<<<(N_EDGES + 255) / 256, 256, 0, stream>>>(row, col, norm, cursor, rows_s, norms_s);

    // layer 1
    k_cvt_w1<<<(F_IN * HID + 255) / 256, 256, 0, stream>>>(W1, w1t);
    k_gemm1_mfma<<<(N_NODES + 127) / 128, 256, 0, stream>>>(x, w1t, hb);
    k_agg1<<<N_NODES, 128, 0, stream>>>(rows_s, norms_s, startp, hb, dinv, b1, h1);

    // layer 2
    k_gemm2<<<(N_NODES * 32 + 255) / 256, 256, 0, stream>>>(h1, W2, h2);
    k_agg2<<<(N_NODES * 32 + 255) / 256, 256, 0, stream>>>(rows_s, norms_s, startp, h2, dinv, b2, out);
}

// Round 4
// 308.388 us; speedup vs baseline: 5.6479x; 1.1464x over previous
//
#include <hip/hip_runtime.h>

#define N_NODES 50000
#define N_EDGES 800000
#define F_IN    512
#define HID     128
#define OUT_F   20
#define SCAN_B  256
#define N_BLK   ((N_NODES + SCAN_B - 1) / SCAN_B)   // 196

typedef __bf16 bf16x8 __attribute__((ext_vector_type(8)));
typedef float  f32x4  __attribute__((ext_vector_type(4)));

// ---------------- degree + edge-count histogram ----------------

__global__ void k_init(float* __restrict__ deg, int* __restrict__ count) {
    int i = blockIdx.x * blockDim.x + threadIdx.x;
    if (i < N_NODES) { deg[i] = 1.0f; count[i] = 0; }  // self-loop weight 1
}

__global__ void k_deg_count(const int* __restrict__ col, const float* __restrict__ w,
                            float* __restrict__ deg, int* __restrict__ count) {
    int e = blockIdx.x * blockDim.x + threadIdx.x;
    if (e < N_EDGES) {
        int c = col[e];
        atomicAdd(&deg[c], w[e]);
        atomicAdd(&count[c], 1);
    }
}

__global__ void k_dinv(float* __restrict__ deg) {
    int i = blockIdx.x * blockDim.x + threadIdx.x;
    if (i < N_NODES) {
        float d = deg[i];
        deg[i] = d > 0.f ? rsqrtf(d) : 0.f;
    }
}

// ---------------- scan (counting-sort offsets) ----------------

__global__ __launch_bounds__(SCAN_B) void k_scan1(const int* __restrict__ count,
                                                  int* __restrict__ bsum) {
    __shared__ int s[SCAN_B];
    int i = blockIdx.x * SCAN_B + threadIdx.x;
    s[threadIdx.x] = (i < N_NODES) ? count[i] : 0;
    __syncthreads();
    for (int off = SCAN_B / 2; off > 0; off >>= 1) {
        if (threadIdx.x < off) s[threadIdx.x] += s[threadIdx.x + off];
        __syncthreads();
    }
    if (threadIdx.x == 0) bsum[blockIdx.x] = s[0];
}

__global__ __launch_bounds__(SCAN_B) void k_scan2(int* __restrict__ bsum,
                                                  int* __restrict__ start) {
    __shared__ int s[SCAN_B];
    int tid = threadIdx.x;
    int v = (tid < N_BLK) ? bsum[tid] : 0;
    s[tid] = v;
    __syncthreads();
    for (int off = 1; off < SCAN_B; off <<= 1) {
        int t = (tid >= off) ? s[tid - off] : 0;
        __syncthreads();
        s[tid] += t;
        __syncthreads();
    }
    if (tid < N_BLK) bsum[tid] = s[tid] - v;   // exclusive
    if (tid == 0) start[N_NODES] = N_EDGES;
}

__global__ __launch_bounds__(SCAN_B) void k_scan3(const int* __restrict__ count,
                                                  const int* __restrict__ bsum,
                                                  int* __restrict__ start,
                                                  int* __restrict__ cursor) {
    __shared__ int s[SCAN_B];
    int i = blockIdx.x * SCAN_B + threadIdx.x;
    int tid = threadIdx.x;
    int v = (i < N_NODES) ? count[i] : 0;
    s[tid] = v;
    __syncthreads();
    for (int off = 1; off < SCAN_B; off <<= 1) {
        int t = (tid >= off) ? s[tid - off] : 0;
        __syncthreads();
        s[tid] += t;
        __syncthreads();
    }
    if (i < N_NODES) {
        int st = bsum[blockIdx.x] + s[tid] - v;
        start[i] = st;
        cursor[i] = st;
    }
}

// fill: counting-sort edges by destination; fold norm computation in
__global__ void k_fill(const int* __restrict__ row, const int* __restrict__ col,
                       const float* __restrict__ w, const float* __restrict__ dinv,
                       int* __restrict__ cursor,
                       int* __restrict__ rows_s, float* __restrict__ norms_s) {
    int e = blockIdx.x * blockDim.x + threadIdx.x;
    if (e < N_EDGES) {
        int r = row[e], c = col[e];
        int pos = atomicAdd(&cursor[c], 1);
        rows_s[pos] = r;
        norms_s[pos] = dinv[r] * w[e] * dinv[c];
    }
}

// ---------------- W1 transpose + bf16 convert: w1t[n][k] = bf16(W1[k][n]) ----------------

__global__ void k_cvt_w1(const float* __restrict__ W1, __bf16* __restrict__ w1t) {
    int g = blockIdx.x * blockDim.x + threadIdx.x;   // g = k*HID + n
    if (g < F_IN * HID) {
        int k = g >> 7;
        int n = g & (HID - 1);
        w1t[(size_t)n * F_IN + k] = (__bf16)W1[g];
    }
}

// ---------------- layer 1 GEMM (MFMA bf16): hb = bf16(x @ W1) ----------------
// 64x128 tile, 4 waves 2x2, wave = 32x64 (2x4 frags of 16x16x32), BK=64, dbuf LDS.
// A: reg-staged fp32->bf16, XOR-swizzled + frag-k-permuted.
// B: global_load_lds direct (linear dest, inverse-swizzled per-lane SOURCE, swz read).

#define BM  64
#define BKK 64

__global__ __launch_bounds__(256) void k_gemm1_mfma(const float* __restrict__ x,
                                                    const __bf16* __restrict__ w1t,
                                                    __bf16* __restrict__ hb) {
    __shared__ __bf16 As[2][BM * BKK];    // 8 KB each
    __shared__ __bf16 Bs[2][HID * BKK];   // 16 KB each
    const int tid  = threadIdx.x;
    const int lane = tid & 63;
    const int wid  = tid >> 6;
    const int wm   = wid >> 1;            // row half (32)
    const int wn   = wid & 1;             // col half (64)
    const int r0   = blockIdx.x * BM;

    f32x4 acc[2][4] = {};
    float4 av[4];

    auto a_issue = [&](int k0) {
#pragma unroll
        for (int i = 0; i < 4; ++i) {
            int c2  = tid + 256 * i;      // 16B chunk id, 1024 total
            int r   = c2 >> 4;            // row 0..63
            int cin = c2 & 15;            // 4-float chunk (k = cin*4)
            int gr  = r0 + r;
            av[i] = (gr < N_NODES)
                ? *(const float4*)(x + (size_t)gr * F_IN + k0 + cin * 4)
                : make_float4(0.f, 0.f, 0.f, 0.f);
        }
    };
    auto a_write = [&](int buf) {
#pragma unroll
        for (int i = 0; i < 4; ++i) {
            int c2  = tid + 256 * i;
            int r   = c2 >> 4;
            int cin = c2 & 15;
            union { __bf16 b[4]; uint2 u; } pk;
            pk.b[0] = (__bf16)av[i].x; pk.b[1] = (__bf16)av[i].y;
            pk.b[2] = (__bf16)av[i].z; pk.b[3] = (__bf16)av[i].w;
            int b32  = cin >> 3, r4 = cin & 7;
            int slot = ((r4 & 3) << 1) | (r4 >> 2);     // frag-k-permute
            int byte = r * (BKK * 2) + (((b32 << 6) + (slot << 3)) ^ ((r & 7) << 4));
            *(uint2*)((char*)(&As[buf][0]) + byte) = pk.u;
        }
    };
    auto b_issue = [&](int buf, int k0) {
#pragma unroll
        for (int i = 0; i < 4; ++i) {
            int cb = wid * 256 + i * 64;      // wave-uniform chunk base
            int c  = cb + lane;               // 16B chunk id, 1024 total
            int cc = c >> 3;                  // dest row (col of W1)
            int s  = c & 7;                   // dest 16B slot in row
            const __bf16* src = w1t + (size_t)cc * F_IN + k0 + ((s ^ (cc & 7)) << 3);
            __builtin_amdgcn_global_load_lds(
                (const __attribute__((address_space(1))) void*)src,
                (__attribute__((address_space(3))) void*)(&Bs[buf][cb * 8]),
                16, 0, 0);
        }
    };
    auto compute = [&](int buf) {
#pragma unroll
        for (int kk = 0; kk < 2; ++kk) {
            bf16x8 a[2], b[4];
#pragma unroll
            for (int mi = 0; mi < 2; ++mi) {
                int r = wm * 32 + mi * 16 + (lane & 15);
                int byte = r * (BKK * 2) + (((kk << 6) + ((lane >> 4) << 4)) ^ ((r & 7) << 4));
                a[mi] = *(const bf16x8*)((const char*)(&As[buf][0]) + byte);
            }
#pragma unroll
            for (int ni = 0; ni < 4; ++ni) {
                int cc = wn * 64 + ni * 16 + (lane & 15);
                int o  = (kk << 6) + ((lane >> 4) << 3);
                int sw = (cc & 7) << 4;
                const char* base = (const char*)(&Bs[buf][0]) + cc * (BKK * 2);
                union { __bf16 h[8]; bf16x8 v; } bb;
                *(uint2*)(&bb.h[0]) = *(const uint2*)(base + (o ^ sw));
                *(uint2*)(&bb.h[4]) = *(const uint2*)(base + ((o + 32) ^ sw));
                b[ni] = bb.v;
            }
#pragma unroll
            for (int mi = 0; mi < 2; ++mi)
#pragma unroll
                for (int ni = 0; ni < 4; ++ni)
                    acc[mi][ni] = __builtin_amdgcn_mfma_f32_16x16x32_bf16(
                        a[mi], b[ni], acc[mi][ni], 0, 0, 0);
        }
    };

    // prologue
    a_issue(0);
    b_issue(0, 0);
    a_write(0);
    __syncthreads();                       // drains vm+lgkm: tile 0 ready

    for (int t = 0; t < 8; ++t) {
        int cur = t & 1, nxt = cur ^ 1;
        if (t < 7) {
            a_issue((t + 1) * BKK);        // loads in flight across compute (T14)
            b_issue(nxt, (t + 1) * BKK);
        }
        compute(cur);
        if (t < 7) a_write(nxt);
        __syncthreads();                   // one barrier per K-step
    }

    // epilogue: C/D col=lane&15, row=(lane>>4)*4+reg
#pragma unroll
    for (int mi = 0; mi < 2; ++mi) {
        int rb = r0 + wm * 32 + mi * 16 + ((lane >> 4) << 2);
#pragma unroll
        for (int rr = 0; rr < 4; ++rr) {
            int gr = rb + rr;
            if (gr < N_NODES) {
#pragma unroll
                for (int ni = 0; ni < 4; ++ni) {
                    int cc = wn * 64 + ni * 16 + (lane & 15);
                    hb[(size_t)gr * HID + cc] = (__bf16)acc[mi][ni][rr];
                }
            }
        }
    }
}

// ---------------- layer 1 aggregation: 1 wave per node, bf16x2 packed ----------------

__device__ inline float blo(unsigned v) { union { unsigned u; float f; } c; c.u = v << 16; return c.f; }
__device__ inline float bhi(unsigned v) { union { unsigned u; float f; } c; c.u = v & 0xffff0000u; return c.f; }

__global__ __launch_bounds__(128) void k_agg1(const int* __restrict__ rows_s,
                                              const float* __restrict__ norms_s,
                                              const int* __restrict__ start,
                                              const __bf16* __restrict__ hb,
                                              const float* __restrict__ dinv,
                                              const float* __restrict__ b1,
                                              float* __restrict__ h1) {
    __shared__ int   sr[2][64];
    __shared__ float sn[2][64];
    const int w    = threadIdx.x >> 6;
    const int lane = threadIdx.x & 63;
    const int c    = blockIdx.x * 2 + w;
    const unsigned* hbu = (const unsigned*)hb;

    float di = dinv[c];
    unsigned sv = hbu[((size_t)c << 6) + lane];
    float a0 = di * di * blo(sv);
    float a1 = di * di * bhi(sv);
    int s0 = start[c], s1 = start[c + 1];
    for (int base = s0; base < s1; base += 64) {
        int m = s1 - base; if (m > 64) m = 64;
        if (lane < m) {                       // wave-synchronous, no barrier
            sr[w][lane] = rows_s[base + lane];
            sn[w][lane] = norms_s[base + lane];
        }
        for (int t = 0; t < m; ++t) {
            float nm = sn[w][t];
            unsigned v = hbu[((size_t)sr[w][t] << 6) + lane];
            a0 = fmaf(nm, blo(v), a0);
            a1 = fmaf(nm, bhi(v), a1);
        }
    }
    float2 bb = *(const float2*)(b1 + 2 * lane);
    a0 += bb.x; a1 += bb.y;
    float2 o2;
    o2.x = a0 > 0.f ? a0 : 0.f;
    o2.y = a1 > 0.f ? a1 : 0.f;
    *(float2*)(h1 + ((size_t)c << 7) + 2 * lane) = o2;
}

// ---------------- layer 2 GEMM: h2 = h1 @ W2  (50000x128 @ 128x20) ----------------

__global__ __launch_bounds__(256) void k_gemm2(const float* __restrict__ h1,
                                               const float* __restrict__ W2,
                                               float* __restrict__ h2) {
    int g = blockIdx.x * blockDim.x + threadIdx.x;
    int i = g >> 5;
    int j = g & 31;
    if (i >= N_NODES || j >= OUT_F) return;
    float acc = 0.f;
    const float* hr = h1 + (size_t)i * HID;
    for (int k = 0; k < HID; ++k) acc = fmaf(hr[k], W2[k * OUT_F + j], acc);
    h2[(size_t)i * OUT_F + j] = acc;
}

// ---------------- layer 2 aggregation ----------------

__global__ __launch_bounds__(256) void k_agg2(const int* __restrict__ rows_s,
                                              const float* __restrict__ norms_s,
                                              const int* __restrict__ start,
                                              const float* __restrict__ h2,
                                              const float* __restrict__ dinv,
                                              const float* __restrict__ b2,
                                              float* __restrict__ out) {
    int g = blockIdx.x * blockDim.x + threadIdx.x;
    int c = g >> 5;
    int j = g & 31;
    if (c >= N_NODES || j >= OUT_F) return;
    float di = dinv[c];
    float acc = di * di * h2[(size_t)c * OUT_F + j] + b2[j];
    int s0 = start[c], s1 = start[c + 1];
    for (int k = s0; k < s1; ++k)
        acc = fmaf(norms_s[k], h2[(size_t)rows_s[k] * OUT_F + j], acc);
    out[(size_t)c * OUT_F + j] = acc;
}

// ---------------- launch ----------------

extern "C" void kernel_launch(void* const* d_in, const int* in_sizes, int n_in,
                              void* d_out, int out_size, void* d_ws, size_t ws_size,
                              hipStream_t stream) {
    const float* x  = (const float*)d_in[0];
    const int*   ei = (const int*)d_in[1];       // [2][E] int32
    const float* ew = (const float*)d_in[2];
    const float* W1 = (const float*)d_in[3];
    const float* b1 = (const float*)d_in[4];
    const float* W2 = (const float*)d_in[5];
    const float* b2 = (const float*)d_in[6];
    float* out = (float*)d_out;

    const int* row = ei;
    const int* col = ei + N_EDGES;

    char* p = (char*)d_ws;
    float* dinv    = (float*)p;  p += (size_t)N_NODES * 4;
    float* h1      = (float*)p;  p += (size_t)N_NODES * HID * 4;
    float* h2      = (float*)p;  p += (size_t)N_NODES * OUT_F * 4;
    float* norms_s = (float*)p;  p += (size_t)N_EDGES * 4;
    __bf16* hb     = (__bf16*)p; p += (size_t)N_NODES * HID * 2;
    __bf16* w1t    = (__bf16*)p; p += (size_t)F_IN * HID * 2;
    int* count     = (int*)p;    p += (size_t)N_NODES * 4;
    int* cursor    = (int*)p;    p += (size_t)N_NODES * 4;
    int* rows_s    = (int*)p;    p += (size_t)N_EDGES * 4;
    int* bsum      = (int*)p;    p += (size_t)N_BLK * 4;
    int* startp    = (int*)p;    p += (size_t)(N_NODES + 1) * 4;

    // norm + CSR build
    k_init<<<N_BLK, 256, 0, stream>>>(dinv, count);
    k_deg_count<<<(N_EDGES + 255) / 256, 256, 0, stream>>>(col, ew, dinv, count);
    k_dinv<<<N_BLK, 256, 0, stream>>>(dinv);
    k_scan1<<<N_BLK, SCAN_B, 0, stream>>>(count, bsum);
    k_scan2<<<1, SCAN_B, 0, stream>>>(bsum, startp);
    k_scan3<<<N_BLK, SCAN_B, 0, stream>>>(count, bsum, startp, cursor);
    k_fill<<<(N_EDGES + 255) / 256, 256, 0, stream>>>(row, col, ew, dinv, cursor, rows_s, norms_s);

    // layer 1
    k_cvt_w1<<<(F_IN * HID + 255) / 256, 256, 0, stream>>>(W1, w1t);
    k_gemm1_mfma<<<(N_NODES + BM - 1) / BM, 256, 0, stream>>>(x, w1t, hb);
    k_agg1<<<N_NODES / 2, 128, 0, stream>>>(rows_s, norms_s, startp, hb, dinv, b1, h1);

    // layer 2
    k_gemm2<<<(N_NODES * 32 + 255) / 256, 256, 0, stream>>>(h1, W2, h2);
    k_agg2<<<(N_NODES * 32 + 255) / 256, 256, 0, stream>>>(rows_s, norms_s, startp, h2, dinv, b2, out);
}